// Round 1
// 102.821 us; speedup vs baseline: 1.0224x; 1.0224x over previous
//
#include <hip/hip_runtime.h>

#define BTOT 1000000

typedef _Float16 f16;
typedef f16 f16x2 __attribute__((ext_vector_type(2)));
typedef f16 f16x8 __attribute__((ext_vector_type(8)));
typedef float f32x2 __attribute__((ext_vector_type(2)));
typedef float f32x4 __attribute__((ext_vector_type(4)));

// 16-lane-row rotate-and-add via DPP (VALU pipe, no LDS traffic).
template<int CTRL>
__device__ __forceinline__ float dpp_add(float v) {
    int pv = __builtin_amdgcn_update_dpp(0, __builtin_bit_cast(int, v),
                                         CTRL, 0xF, 0xF, true);
    return v + __builtin_bit_cast(float, pv);
}
// pure DPP shuffle (quad_perm / row_ror), result only
template<int CTRL>
__device__ __forceinline__ float dpp_mov(float v) {
    int pv = __builtin_amdgcn_update_dpp(0, __builtin_bit_cast(int, v),
                                         CTRL, 0xF, 0xF, true);
    return __builtin_bit_cast(float, pv);
}
#define DPP_XOR1 0xB1   // quad_perm [1,0,3,2]
#define DPP_XOR2 0x4E   // quad_perm [2,3,0,1]

// Single fused kernel: per-block prep (replaces setup_kernel) + streaming body.
// (256,4): per-tile epilogue keeps live state ~115 regs -> fits 128/wave.
// LDS: 64*65*4 + 64*4 + 256*4 + 4 ~= 17.9 KB -> 4 blocks/CU = 71.8 KB, fits.
__global__ __launch_bounds__(256, 4) void netc_kernel(
    const float* __restrict__ x,  const float* __restrict__ y,
    const float* __restrict__ ex, const float* __restrict__ ey,
    const float* __restrict__ W1, const float* __restrict__ b1,
    const float* __restrict__ W2, const float* __restrict__ b2,
    const float* __restrict__ W3,
    float* __restrict__ out)
{
    const int tid  = threadIdx.x;
    const int lane = tid & 63;
    const int wv   = tid >> 6;
    const int quad = lane >> 4;
    const int nl   = lane & 15;

    __shared__ float w2s[64 * 65];   // padded: row stride 65 -> conflict-free
    __shared__ float h1s[64];
    __shared__ float part[4 * 64];
    __shared__ float utgt_s;

    // ---------- issue first input loads NOW; latency hides under prep ----------
    const int nwaves = (gridDim.x * blockDim.x) >> 6;   // 4096
    const int estep  = nwaves << 6;
    int e0 = (((blockIdx.x << 2) + wv) << 6) + lane;

    float axv = 0.f, ayv = 0.f, aexv = 0.f, aeyv = 0.f;
    float bxv = 0.f, byv = 0.f, bexv = 0.f, beyv = 0.f;
    if (e0 < BTOT)         { axv = x[e0]; ayv = y[e0]; aexv = ex[e0]; aeyv = ey[e0]; }
    if (e0 + estep < BTOT) { int p = e0 + estep; bxv = x[p]; byv = y[p]; bexv = ex[p]; beyv = ey[p]; }

    // ---------- per-block prep (was setup_kernel; ~2 us, fully overlapped) ----------
    {
        const float4* W2v = (const float4*)W2;
        #pragma unroll
        for (int r = 0; r < 4; ++r) {
            int idx = r * 256 + tid;           // 1024 float4s total
            float4 f = W2v[idx];
            int g = idx * 4, row = g >> 6, col = g & 63;
            float* p = &w2s[row * 65 + col];
            p[0] = f.x; p[1] = f.y; p[2] = f.z; p[3] = f.w;
        }
        const float T = 6.2562059f;  // 0.62562059 * 10
        if (tid < 64)
            h1s[tid] = fmaxf(0.f, W1[2 * tid] * T + W1[2 * tid + 1] * T + b1[tid]);
        __syncthreads();
        {
            int r = tid & 63, kq = tid >> 6;
            float p = 0.f;
            #pragma unroll
            for (int k = 0; k < 16; ++k)
                p = fmaf(w2s[r * 65 + kq * 16 + k], h1s[kq * 16 + k], p);
            part[kq * 64 + r] = p;
        }
        __syncthreads();
        if (tid < 64) {
            float h2 = b2[tid] + part[tid] + part[64 + tid] + part[128 + tid] + part[192 + tid];
            float pr = fmaxf(0.f, h2) * W3[tid];
            #pragma unroll
            for (int m = 1; m < 64; m <<= 1) pr += __shfl_xor(pr, m, 64);
            if (tid == 0) utgt_s = pr;     // b3 cancels in u(x)-u(tgt)
        }
        __syncthreads();
    }
    const float u_tgt = utgt_s;
    const float one_minus_ut = 1.0f - u_tgt;

    // ---------- build per-lane register images (same for all 4 waves) ----------
    // B-fragments for layer-2: lane (quad,nl) holds W2[n*16+nl][ks*32+quad*8+j].
    // LDS reads conflict-free: bank = (nl*65 + c) % 32 distinct across 16 lanes.
    f16x8 bfrag[4][2];
    #pragma unroll
    for (int n = 0; n < 4; ++n)
        #pragma unroll
        for (int ks = 0; ks < 2; ++ks) {
            f16x8 f;
            #pragma unroll
            for (int j = 0; j < 8; ++j)
                f[j] = (f16)w2s[(n * 16 + nl) * 65 + ks * 32 + quad * 8 + j];
            bfrag[n][ks] = f;
        }
    f16x2 w1a[8], w1b[8], b1p[8];
    #pragma unroll
    for (int i = 0; i < 8; ++i) {
        int kk = (i < 4) ? (quad * 8 + 2 * i) : (32 + quad * 8 + 2 * (i - 4));
        w1a[i] = f16x2{(f16)W1[2 * kk],     (f16)W1[2 * kk + 2]};
        w1b[i] = f16x2{(f16)W1[2 * kk + 1], (f16)W1[2 * kk + 3]};
        b1p[i] = f16x2{(f16)b1[kk],         (f16)b1[kk + 1]};
    }
    float w3v[4], b2v[4];
    #pragma unroll
    for (int n = 0; n < 4; ++n) { w3v[n] = W3[n * 16 + nl]; b2v[n] = b2[n * 16 + nl]; }

    const f16x2 zero2 = {(f16)0.f, (f16)0.f};
    const int srcb = (((nl >> 2) << 4) + quad * 4 + (nl & 3)) << 2;
    const bool o1 = (nl & 1), o2 = (nl & 2);

    auto body = [&](int ee, float& rx, float& ry, float& rex, float& rey) {
        // consume buffer (issued 2 bodies ago -> arrived), then refill it
        float cx = rx, cy = ry, cex = rex, cey = rey;
        int pe = ee + 2 * estep;
        if (pe < BTOT) { rx = x[pe]; ry = y[pe]; rex = ex[pe]; rey = ey[pe]; }

        float av = cx + cex, bv = cy + cey;
        f16x2 pab = {(f16)av, (f16)bv};
        int pv = __builtin_bit_cast(int, pab);

        // Hill math early — dy needs no u -> store now
        float xs = cx * 0.1f, ys = cy * 0.1f;
        float x2 = xs * xs, y2 = ys * ys;
        float invx = __fdividef(1.0f, 0.25f + x2);
        float invy = __fdividef(1.0f, 0.25f + y2);
        float hx = x2 * invx, hy = y2 * invy;
        float gx = 0.25f * invx, gy = 0.25f * invy;
        float cdx = 10.f * hx;
        float base_dx = fmaf(cdx, one_minus_ut, fmaf(2.f, gy, -11.f * xs));
        float dy = fmaf(10.f, hy, fmaf(2.f, gx, -11.f * ys));
        out[BTOT + ee]     = dy;
        out[3 * BTOT + ee] = -dy;

        // distribute A-pairs: tile t gets element ee_base + t*16 + nl
        f16x2 pt[4];
        #pragma unroll
        for (int t = 0; t < 4; ++t)
            pt[t] = __builtin_bit_cast(f16x2,
                __builtin_amdgcn_ds_bpermute((t * 16 + nl) << 2, pv));

        float ur[4];
        #pragma unroll
        for (int t = 0; t < 4; ++t) {
            // acc init with b2 (per-tile: only 16 live acc regs)
            f32x4 acc[4];
            #pragma unroll
            for (int n = 0; n < 4; ++n)
                acc[n] = f32x4{b2v[n], b2v[n], b2v[n], b2v[n]};

            f16x2 a2 = {pt[t][0], pt[t][0]};
            f16x2 bb = {pt[t][1], pt[t][1]};
            union { f16x2 h2[8]; f16x8 fr[2]; } u;
            #pragma unroll
            for (int i = 0; i < 8; ++i) {
                f16x2 h = a2 * w1a[i] + (bb * w1b[i] + b1p[i]);
                u.h2[i] = __builtin_elementwise_max(h, zero2);
            }
            __builtin_amdgcn_s_setprio(1);
            #pragma unroll
            for (int n = 0; n < 4; ++n) {
                acc[n] = __builtin_amdgcn_mfma_f32_16x16x32_f16(u.fr[0], bfrag[n][0], acc[n], 0, 0, 0);
                acc[n] = __builtin_amdgcn_mfma_f32_16x16x32_f16(u.fr[1], bfrag[n][1], acc[n], 0, 0, 0);
            }
            __builtin_amdgcn_s_setprio(0);

            // relu + w3 fold (packed f32)
            f32x2 p01 = {0.f, 0.f}, p23 = {0.f, 0.f};
            #pragma unroll
            for (int n = 0; n < 4; ++n) {
                f32x2 lo = {acc[n][0], acc[n][1]};
                f32x2 hi = {acc[n][2], acc[n][3]};
                lo = __builtin_elementwise_max(lo, f32x2{0.f, 0.f});
                hi = __builtin_elementwise_max(hi, f32x2{0.f, 0.f});
                f32x2 w = {w3v[n], w3v[n]};
                p01 += lo * w;
                p23 += hi * w;
            }
            // component-interleaved butterfly reduce (14 VALU vs 34):
            // stage1 (xor1, quad_perm): pair-sum, lane keeps component (nl&1)
            float a_keep = o1 ? p01[1] : p01[0];
            float a_send = o1 ? p01[0] : p01[1];
            float b_keep = o1 ? p23[1] : p23[0];
            float b_send = o1 ? p23[0] : p23[1];
            float a = a_keep + dpp_mov<DPP_XOR1>(a_send);
            float b = b_keep + dpp_mov<DPP_XOR1>(b_send);
            // stage2 (xor2): quad-sum, lane keeps component (nl&3)
            float c_keep = o2 ? b : a;
            float c_send = o2 ? a : b;
            float c = c_keep + dpp_mov<DPP_XOR2>(c_send);
            // stages 3-4: sum the 4 quads (rotation preserves nl&3)
            c = dpp_add<0x124>(c);  // row_ror:4
            c = dpp_add<0x128>(c);  // row_ror:8
            ur[t] = c;   // = U(elem t*16 + quad*4 + (nl&3)), same map as before
        }

        // send = ur[(nl>>2)&3]; sender lane s holds u for elem ((s&15)>>2)*16+(s>>4)*4+(s&3)
        float s01  = (nl & 4) ? ur[1] : ur[0];
        float s23  = (nl & 4) ? ur[3] : ur[2];
        float send = (nl & 8) ? s23 : s01;
        float u_raw = __builtin_bit_cast(float,
            __builtin_amdgcn_ds_bpermute(srcb, __builtin_bit_cast(int, send)));

        float dx = fmaf(cdx, u_raw, base_dx);
        out[ee]            = dx;
        out[2 * BTOT + ee] = -dx;
    };

    for (int e = e0; e < BTOT; e += 2 * estep) {
        body(e, axv, ayv, aexv, aeyv);
        int e1 = e + estep;
        if (e1 < BTOT)
            body(e1, bxv, byv, bexv, beyv);
    }
}

extern "C" void kernel_launch(void* const* d_in, const int* in_sizes, int n_in,
                              void* d_out, int out_size, void* d_ws, size_t ws_size,
                              hipStream_t stream) {
    const float* x  = (const float*)d_in[0];
    const float* y  = (const float*)d_in[1];
    const float* ex = (const float*)d_in[2];
    const float* ey = (const float*)d_in[3];
    const float* W1 = (const float*)d_in[4];
    const float* b1 = (const float*)d_in[5];
    const float* W2 = (const float*)d_in[6];
    const float* b2 = (const float*)d_in[7];
    const float* W3 = (const float*)d_in[8];
    float* out = (float*)d_out;
    (void)d_ws; (void)ws_size;

    // single fused kernel: 1024 blocks x 4 waves = 4096 waves = 4 blocks/CU resident
    netc_kernel<<<1024, 256, 0, stream>>>(x, y, ex, ey, W1, b1, W2, b2, W3, out);
}